// Round 6
// baseline (1190.766 us; speedup 1.0000x reference)
//
#include <hip/hip_runtime.h>
#include <hip/hip_bf16.h>
#include <math.h>

#define EPS 1e-5f

typedef __hip_bfloat16 bf16;
typedef short short8 __attribute__((ext_vector_type(8)));
typedef float float4v __attribute__((ext_vector_type(4)));

__device__ __forceinline__ float toF(float v) { return v; }
__device__ __forceinline__ float toF(bf16 v) { return __bfloat162float(v); }
__device__ __forceinline__ void stF(float* p, float v) { *p = v; }
__device__ __forceinline__ void stF(bf16* p, float v) { *p = __float2bfloat16(v); }
__device__ __forceinline__ short f2bs(float v) {
    bf16 b = __float2bfloat16(v);
    return *reinterpret_cast<short*>(&b);
}
__device__ __forceinline__ void stF(short* p, float v) { *p = f2bs(v); }
__device__ __forceinline__ float bs2f(short s) {
    unsigned u = ((unsigned)(unsigned short)s) << 16;
    return __uint_as_float(u);
}

// ---------------- block reduction (blockDim.x == 256) ----------------
__device__ __forceinline__ float block_reduce_sum(float v) {
    __shared__ float s[256];
    int t = threadIdx.x;
    s[t] = v;
    __syncthreads();
    #pragma unroll
    for (int st = 128; st > 0; st >>= 1) {
        if (t < st) s[t] += s[t + st];
        __syncthreads();
    }
    float r = s[0];
    __syncthreads();
    return r;
}

// ---------------- ternarize -> bf16 sign {-1,0,+1} + fp32 alpha ----------------
// perm9: write k' = tap*256 + ci for K=2304 (i = ci*9 + tap)
__global__ void ternarize_kernel(const float* __restrict__ w, short* __restrict__ wt,
                                 float* __restrict__ alpha, int K, int perm9) {
    int f = blockIdx.x;
    const float* wf = w + (size_t)f * K;
    short* wtf = wt + (size_t)f * K;

    float s = 0.f;
    for (int i = threadIdx.x; i < K; i += blockDim.x) s += fabsf(wf[i]);
    float total = block_reduce_sum(s);
    float delta = 0.7f * total / (float)K;

    float sm = 0.f, cm = 0.f;
    for (int i = threadIdx.x; i < K; i += blockDim.x) {
        float a = fabsf(wf[i]);
        if (a > delta) { sm += a; cm += 1.f; }
    }
    sm = block_reduce_sum(sm);
    cm = block_reduce_sum(cm);
    if (threadIdx.x == 0) alpha[f] = sm / (cm + 1e-8f);

    for (int i = threadIdx.x; i < K; i += blockDim.x) {
        float v = wf[i];
        float a = fabsf(v);
        short sv = (a > delta) ? ((v > 0.f) ? (short)0x3F80 : (short)0xBF80) : (short)0;
        int k = i;
        if (perm9) { int ci = i / 9; int tap = i - ci * 9; k = tap * 256 + ci; }
        wtf[k] = sv;
    }
}

// ---------------- fp32 -> bf16 cast ----------------
__global__ void f2bf_kernel(const float* __restrict__ in, short* __restrict__ out, int n) {
    int i = blockIdx.x * blockDim.x + threadIdx.x;
    if (i < n) out[i] = f2bs(in[i]);
}

// ---------------- fold scale into ternary signs: wf = sign * scale[k] ----------------
__global__ void foldw_kernel(const short* __restrict__ sign, const float* __restrict__ scale,
                             short* __restrict__ wf, int K, int total) {
    int i = blockIdx.x * blockDim.x + threadIdx.x;
    if (i >= total) return;
    int k = i % K;
    wf[i] = f2bs(bs2f(sign[i]) * scale[k]);
}

// ---------------- fold bias: bias[m] = alpha[m] * dot(sign[m,:], shift) ----------------
__global__ void foldb_kernel(const short* __restrict__ sign, const float* __restrict__ shift,
                             const float* __restrict__ alpha, float* __restrict__ bias, int K) {
    int m = blockIdx.x;
    float s = 0.f;
    for (int k = threadIdx.x; k < K; k += blockDim.x)
        s += bs2f(sign[(size_t)m * K + k]) * shift[k];
    s = block_reduce_sum(s);
    if (threadIdx.x == 0) bias[m] = alpha[m] * s;
}

// ---------------- column stats on T-layout [rows][C] bf16; C = CG*8 ----------------
// accumulators must be pre-zeroed
template <int CG>
__global__ __launch_bounds__(256) void colstats_kernel(
    const short* __restrict__ src, float* __restrict__ sum, float* __restrict__ sq,
    int totalVec) {
    __shared__ float lds[256 * 16];
    int t = threadIdx.x;
    float s[8], q[8];
    #pragma unroll
    for (int k = 0; k < 8; k++) { s[k] = 0.f; q[k] = 0.f; }
    for (int v = blockIdx.x * 256 + t; v < totalVec; v += gridDim.x * 256) {
        short tmp[8];
        *(int4*)tmp = *(const int4*)(src + (size_t)v * 8);
        #pragma unroll
        for (int k = 0; k < 8; k++) {
            float f = bs2f(tmp[k]);
            s[k] += f;
            q[k] += f * f;
        }
    }
    #pragma unroll
    for (int k = 0; k < 8; k++) { lds[t * 16 + k] = s[k]; lds[t * 16 + 8 + k] = q[k]; }
    __syncthreads();
    if (t < CG) {
        #pragma unroll
        for (int r = 1; r < 256 / CG; r++)
            for (int k = 0; k < 16; k++) lds[t * 16 + k] += lds[(t + r * CG) * 16 + k];
        // channel group for thread t is ((blockIdx*256 + t) % CG) == t since CG | 256
        #pragma unroll
        for (int k = 0; k < 8; k++) {
            atomicAdd(&sum[t * 8 + k], lds[t * 16 + k]);
            atomicAdd(&sq[t * 8 + k], lds[t * 16 + 8 + k]);
        }
    }
}

// ---------------- BN finalize ----------------
__global__ void bn_finalize_kernel(const float* __restrict__ sum, const float* __restrict__ sq,
                                   const float* __restrict__ g, const float* __restrict__ b,
                                   float* __restrict__ scale, float* __restrict__ shift,
                                   int C, float cnt) {
    int c = blockIdx.x * blockDim.x + threadIdx.x;
    if (c >= C) return;
    float mean = sum[c] / cnt;
    float var = fmaxf(sq[c] / cnt - mean * mean, 0.f);
    float r = rsqrtf(var + EPS);
    float sc = g[c] * r;
    scale[c] = sc;
    shift[c] = b[c] - mean * sc;
}

// ---------------- transpose NCHW fp32 -> xT[(n*SP+p)][C] bf16 (raw) ----------------
__global__ __launch_bounds__(256) void transpose_kernel(
    const float* __restrict__ in, short* __restrict__ Bt, int C, int SP) {
    __shared__ short tile[64][65];
    int n = blockIdx.z;
    int ci0 = blockIdx.y * 64;
    int p0 = blockIdx.x * 64;
    int tx = threadIdx.x & 63;
    int ty4 = threadIdx.x >> 6;

    int p = p0 + tx;
    bool pok = p < SP;
    const float* base = in + ((size_t)n * C + ci0) * SP;
    #pragma unroll
    for (int r = 0; r < 16; r++) {
        int ci = ty4 + r * 4;
        float v = 0.f;
        if (pok) v = base[(size_t)ci * SP + p];
        tile[tx][ci] = f2bs(v);
    }
    __syncthreads();
    #pragma unroll
    for (int r = 0; r < 16; r++) {
        int pl = ty4 + r * 4;
        int pw = p0 + pl;
        if (pw < SP)
            Bt[((size_t)n * SP + pw) * C + ci0 + tx] = tile[pl][tx];
    }
}

// ---------------- im2col (tap-major K) from h1t, with bn2 affine ----------------
// B2t[c][tap*256+ci]; vector unit = 8 channels (int4)
__global__ void im2col_t_kernel(const short* __restrict__ h1t,
                                const float* __restrict__ scale, const float* __restrict__ shift,
                                short* __restrict__ B2t, int totalVec) {
    int i = blockIdx.x * blockDim.x + threadIdx.x;
    if (i >= totalVec) return;
    int cg = i & 31;
    int rest = i >> 5;
    int tap = rest % 9;
    int c = rest / 9;
    int kh = tap / 3, kw = tap - kh * 3;
    int n = c / 196, pp = c - n * 196;
    int oh = pp / 14, ow = pp - oh * 14;
    int ih = 2 * oh - 1 + kh, iw = 2 * ow - 1 + kw;
    short tmp[8];
    if ((unsigned)ih < 28u && (unsigned)iw < 28u) {
        int src = n * 784 + ih * 28 + iw;
        *(int4*)tmp = *(const int4*)(h1t + (size_t)src * 256 + cg * 8);
        #pragma unroll
        for (int k2 = 0; k2 < 8; k2++) {
            int ch = cg * 8 + k2;
            tmp[k2] = f2bs(bs2f(tmp[k2]) * scale[ch] + shift[ch]);
        }
    } else {
        #pragma unroll
        for (int k2 = 0; k2 < 8; k2++) tmp[k2] = 0;
    }
    *(int4*)(B2t + (size_t)c * 2304 + tap * 256 + cg * 8) = *(int4*)tmp;
}

// ---------------- flipped MFMA GEMM: D[pix][ch] ----------------
// Act: [NTsrc][K] bf16 (rows = pixels), Wt: [M][K] bf16 (rows = channels)
// outT: [NTdst][M].  MODE: 0 = raw, 1 = alpha[col]*acc, 2 = alpha[col]*acc + bias[col]
template <bool REMAP, int MODE, typename TOut>
__global__ __launch_bounds__(256) void gemm_t_kernel(
    const short* __restrict__ Act, const short* __restrict__ Wt,
    const float* __restrict__ alpha, const float* __restrict__ bias,
    TOut* __restrict__ outT, int M, int K) {
    __shared__ short As[128 * 32];
    __shared__ short Bs[128 * 32];
    int t = threadIdx.x;
    int pix0 = blockIdx.x * 128;
    int ch0 = blockIdx.y * 128;
    int w = t >> 6, l = t & 63;
    int wm = (w >> 1) * 64, wn = (w & 1) * 64;
    int r0 = t >> 2;
    int kg = (t & 3) * 8;

    int pr0 = pix0 + r0, pr1 = pix0 + r0 + 64;
    if (REMAP) {
        int n0 = pr0 / 196, pp0 = pr0 - n0 * 196, oh0 = pp0 / 14, ow0 = pp0 - oh0 * 14;
        pr0 = n0 * 784 + oh0 * 56 + ow0 * 2;
        int n1 = pr1 / 196, pp1 = pr1 - n1 * 196, oh1 = pp1 / 14, ow1 = pp1 - oh1 * 14;
        pr1 = n1 * 784 + oh1 * 56 + ow1 * 2;
    }
    const short* a0 = Act + (size_t)pr0 * K;
    const short* a1 = Act + (size_t)pr1 * K;
    const short* b0 = Wt + (size_t)(ch0 + r0) * K;
    const short* b1 = Wt + (size_t)(ch0 + r0 + 64) * K;

    float4v acc[4][4];
    #pragma unroll
    for (int i = 0; i < 4; i++)
        #pragma unroll
        for (int j = 0; j < 4; j++) acc[i][j] = (float4v)0.f;

    int lm = (l >> 4);
    int lc = l & 15;

    for (int k0 = 0; k0 < K; k0 += 32) {
        int4 av0 = *(const int4*)(a0 + k0 + kg);
        int4 av1 = *(const int4*)(a1 + k0 + kg);
        int4 bv0 = *(const int4*)(b0 + k0 + kg);
        int4 bv1 = *(const int4*)(b1 + k0 + kg);
        __syncthreads();
        *(int4*)&As[r0 * 32 + kg] = av0;
        *(int4*)&As[(r0 + 64) * 32 + kg] = av1;
        *(int4*)&Bs[r0 * 32 + kg] = bv0;
        *(int4*)&Bs[(r0 + 64) * 32 + kg] = bv1;
        __syncthreads();

        short8 af[4], bfr[4];
        #pragma unroll
        for (int i = 0; i < 4; i++)
            af[i] = *(const short8*)&As[(wm + i * 16 + lc) * 32 + lm * 8];
        #pragma unroll
        for (int j = 0; j < 4; j++)
            bfr[j] = *(const short8*)&Bs[(wn + j * 16 + lc) * 32 + lm * 8];
        #pragma unroll
        for (int i = 0; i < 4; i++)
            #pragma unroll
            for (int j = 0; j < 4; j++)
                acc[i][j] = __builtin_amdgcn_mfma_f32_16x16x32_bf16(af[i], bfr[j], acc[i][j], 0, 0, 0);
    }

    // D row = pixel = pix0+wm+i*16+lm*4+r; col = channel = ch0+wn+j*16+lc
    #pragma unroll
    for (int j = 0; j < 4; j++) {
        int col = ch0 + wn + j * 16 + lc;
        float al = (MODE >= 1) ? alpha[col] : 1.f;
        float bi = (MODE == 2) ? bias[col] : 0.f;
        #pragma unroll
        for (int i = 0; i < 4; i++) {
            #pragma unroll
            for (int r = 0; r < 4; r++) {
                int pix = pix0 + wm + i * 16 + lm * 4 + r;
                float v = acc[i][j][r] * al + bi;
                stF(&outT[(size_t)pix * M + col], v);
            }
        }
    }
}

// ---------------- final: out[n][c][p] = outT[pix][c] + scT[pix][c]*scale[c]+shift[c] ----------------
__global__ __launch_bounds__(256) void combine_kernel(
    const float* __restrict__ outT, const short* __restrict__ scT,
    const float* __restrict__ scale, const float* __restrict__ shift,
    float* __restrict__ out) {
    __shared__ float tile[64][65];
    int pix0 = blockIdx.x * 64;   // 196 blocks (12544/64)
    int ch0 = blockIdx.y * 64;    // 16 blocks
    int tx = threadIdx.x & 63;
    int ph = threadIdx.x >> 6;    // 0..3
    float sc_ = scale[ch0 + tx];
    float sh_ = shift[ch0 + tx];
    #pragma unroll
    for (int i2 = 0; i2 < 16; i2++) {
        int pr = ph + i2 * 4;
        size_t base = (size_t)(pix0 + pr) * 1024 + ch0 + tx;
        tile[pr][tx] = outT[base] + bs2f(scT[base]) * sc_ + sh_;
    }
    __syncthreads();
    int pix = pix0 + tx;
    int n = pix / 196, p = pix - n * 196;
    #pragma unroll
    for (int i2 = 0; i2 < 16; i2++) {
        int ch = ch0 + ph + i2 * 4;
        out[((size_t)n * 1024 + ch) * 196 + p] = tile[tx][ph + i2 * 4];
    }
}

extern "C" void kernel_launch(void* const* d_in, const int* in_sizes, int n_in,
                              void* d_out, int out_size, void* d_ws, size_t ws_size,
                              hipStream_t stream) {
    const float* x      = (const float*)d_in[0];   // (64,512,28,28)
    const float* bn1_g  = (const float*)d_in[1];
    const float* bn1_b  = (const float*)d_in[2];
    const float* w1     = (const float*)d_in[3];   // (256,512,1,1)
    const float* bn2_g  = (const float*)d_in[4];
    const float* bn2_b  = (const float*)d_in[5];
    const float* w2     = (const float*)d_in[6];   // (256,256,3,3)
    const float* bn3_g  = (const float*)d_in[7];
    const float* bn3_b  = (const float*)d_in[8];
    const float* w3     = (const float*)d_in[9];   // (1024,256,1,1)
    const float* ds_w   = (const float*)d_in[10];  // (1024,512,1,1) NOT ternarized
    const float* dbn_g  = (const float*)d_in[11];
    const float* dbn_b  = (const float*)d_in[12];
    float* out = (float*)d_out;

    const int N = 64, C1 = 512, C2 = 256, C3 = 1024;
    const int SP1 = 784, SP2 = 196;
    const int NT1 = N * SP1;   // 50176
    const int NT2 = N * SP2;   // 12544

    // ---- workspace (lifetime-aliased; ~119 MB total) ----
    char* wsb = (char*)d_ws;
    size_t off = 0;
    auto alloc = [&](size_t bytes) { char* p = wsb + off; off += (bytes + 255) & ~(size_t)255; return p; };

    // pool hosts (in time order): xT [NT1][512] bf16 (51.4MB) -> B2t [NT2][2304] bf16 (57.8MB)
    //                             -> outT [NT2][1024] fp32 (51.4MB)
    char* pool = alloc((size_t)NT2 * 2304 * 2);
    short* xT   = (short*)pool;
    short* B2t  = (short*)pool;
    float* outT = (float*)pool;
    short* scT = (short*)alloc((size_t)NT2 * C3 * 2);   // 25.7MB, lives G4 -> combine
    short* h1t = (short*)alloc((size_t)NT1 * C2 * 2);   // 25.7MB
    short* h2t = (short*)alloc((size_t)NT2 * C2 * 2);   // 6.4MB
    short* w1t  = (short*)alloc((size_t)C2 * C1 * 2);   // signs
    short* w2t  = (short*)alloc((size_t)C2 * C2 * 9 * 2); // signs, tap-major perm
    short* w3t  = (short*)alloc((size_t)C3 * C2 * 2);   // signs
    short* dswb = (short*)alloc((size_t)C3 * C1 * 2);
    short* w1f  = (short*)alloc((size_t)C2 * C1 * 2);   // sign*scale1
    short* w3f  = (short*)alloc((size_t)C3 * C2 * 2);   // sign*scale3
    float* alpha1 = (float*)alloc(C2 * 4);
    float* alpha2 = (float*)alloc(C2 * 4);
    float* alpha3 = (float*)alloc(C3 * 4);
    float* bias1  = (float*)alloc(C2 * 4);
    float* bias3  = (float*)alloc(C3 * 4);
    float* scale1 = (float*)alloc(C1 * 4);
    float* shift1 = (float*)alloc(C1 * 4);
    float* scale2 = (float*)alloc(C2 * 4);
    float* shift2 = (float*)alloc(C2 * 4);
    float* scale3 = (float*)alloc(C2 * 4);
    float* shift3 = (float*)alloc(C2 * 4);
    float* scaled = (float*)alloc(C3 * 4);
    float* shiftd = (float*)alloc(C3 * 4);
    float* acc_base = (float*)alloc((size_t)(C1 + C2 + C2 + C3) * 2 * 4);
    float* sum1 = acc_base;  float* sq1 = sum1 + C1;
    float* sum2 = sq1 + C1;  float* sq2 = sum2 + C2;
    float* sum3 = sq2 + C2;  float* sq3 = sum3 + C2;
    float* sumd = sq3 + C2;  float* sqd = sumd + C3;
    (void)ws_size; (void)in_sizes; (void)n_in; (void)out_size;

    hipMemsetAsync(acc_base, 0, (size_t)(C1 + C2 + C2 + C3) * 2 * 4, stream);

    // weights: ternary signs (+ permuted K for w2), ds_w raw cast
    ternarize_kernel<<<C2, 256, 0, stream>>>(w1, w1t, alpha1, C1, 0);
    ternarize_kernel<<<C2, 256, 0, stream>>>(w2, w2t, alpha2, C2 * 9, 1);
    ternarize_kernel<<<C3, 256, 0, stream>>>(w3, w3t, alpha3, C2, 0);
    f2bf_kernel<<<(C3 * C1 + 255) / 256, 256, 0, stream>>>(ds_w, dswb, C3 * C1);

    // xT = transpose(x) raw bf16
    transpose_kernel<<<dim3(13, C1 / 64, N), 256, 0, stream>>>(x, xT, C1, SP1);

    // GEMM4 (ds conv): scT = xT[remap] . dswb^T   (M=1024, K=512)
    gemm_t_kernel<true, 0, short><<<dim3(NT2 / 128, C3 / 128), 256, 0, stream>>>(
        xT, dswb, nullptr, nullptr, scT, C3, C1);
    colstats_kernel<128><<<1024, 256, 0, stream>>>(scT, sumd, sqd, NT2 * (C3 / 8));
    bn_finalize_kernel<<<(C3 + 255) / 256, 256, 0, stream>>>(sumd, sqd, dbn_g, dbn_b,
                                                             scaled, shiftd, C3, (float)(NT2));

    // bn1 from xT; fold into w1
    colstats_kernel<64><<<1024, 256, 0, stream>>>(xT, sum1, sq1, NT1 * (C1 / 8));
    bn_finalize_kernel<<<(C1 + 255) / 256, 256, 0, stream>>>(sum1, sq1, bn1_g, bn1_b,
                                                             scale1, shift1, C1, (float)(NT1));
    foldw_kernel<<<(C2 * C1 + 255) / 256, 256, 0, stream>>>(w1t, scale1, w1f, C1, C2 * C1);
    foldb_kernel<<<C2, 256, 0, stream>>>(w1t, shift1, alpha1, bias1, C1);

    // GEMM1: h1t = xT . w1f^T * alpha1 + bias1   (M=256, K=512)
    gemm_t_kernel<false, 2, short><<<dim3(NT1 / 128, C2 / 128), 256, 0, stream>>>(
        xT, w1f, alpha1, bias1, h1t, C2, C1);

    // bn2 from h1t; im2col with affine
    colstats_kernel<32><<<1024, 256, 0, stream>>>(h1t, sum2, sq2, NT1 * (C2 / 8));
    bn_finalize_kernel<<<(C2 + 255) / 256, 256, 0, stream>>>(sum2, sq2, bn2_g, bn2_b,
                                                             scale2, shift2, C2, (float)(NT1));
    {
        int totalVec = NT2 * 288;  // 2304/8 per pixel
        im2col_t_kernel<<<(totalVec + 255) / 256, 256, 0, stream>>>(
            h1t, scale2, shift2, B2t, totalVec);
    }

    // GEMM2: h2t = B2t . w2t^T * alpha2   (M=256, K=2304)
    gemm_t_kernel<false, 1, short><<<dim3(NT2 / 128, C2 / 128), 256, 0, stream>>>(
        B2t, w2t, alpha2, nullptr, h2t, C2, C2 * 9);

    // bn3 from h2t; fold into w3
    colstats_kernel<32><<<512, 256, 0, stream>>>(h2t, sum3, sq3, NT2 * (C2 / 8));
    bn_finalize_kernel<<<(C2 + 255) / 256, 256, 0, stream>>>(sum3, sq3, bn3_g, bn3_b,
                                                             scale3, shift3, C2, (float)(NT2));
    foldw_kernel<<<(C3 * C2 + 255) / 256, 256, 0, stream>>>(w3t, scale3, w3f, C2, C3 * C2);
    foldb_kernel<<<C3, 256, 0, stream>>>(w3t, shift3, alpha3, bias3, C2);

    // GEMM3: outT = h2t . w3f^T * alpha3 + bias3   (M=1024, K=256, fp32 out)
    gemm_t_kernel<false, 2, float><<<dim3(NT2 / 128, C3 / 128), 256, 0, stream>>>(
        h2t, w3f, alpha3, bias3, outT, C3, C2);

    // final: out = outT + dsbn(scT), transposed to NCHW
    combine_kernel<<<dim3(NT2 / 64, C3 / 64), 256, 0, stream>>>(
        outT, scT, scaled, shiftd, out);
}

// Round 7
// 599.601 us; speedup vs baseline: 1.9859x; 1.9859x over previous
//
#include <hip/hip_runtime.h>
#include <hip/hip_bf16.h>
#include <math.h>

#define EPS 1e-5f

typedef __hip_bfloat16 bf16;
typedef short short8 __attribute__((ext_vector_type(8)));
typedef float float4v __attribute__((ext_vector_type(4)));

__device__ __forceinline__ float toF(float v) { return v; }
__device__ __forceinline__ float toF(bf16 v) { return __bfloat162float(v); }
__device__ __forceinline__ void stF(float* p, float v) { *p = v; }
__device__ __forceinline__ void stF(bf16* p, float v) { *p = __float2bfloat16(v); }
__device__ __forceinline__ short f2bs(float v) {
    bf16 b = __float2bfloat16(v);
    return *reinterpret_cast<short*>(&b);
}
__device__ __forceinline__ void stF(short* p, float v) { *p = f2bs(v); }
__device__ __forceinline__ float bs2f(short s) {
    unsigned u = ((unsigned)(unsigned short)s) << 16;
    return __uint_as_float(u);
}

// ---------------- block reduction (blockDim.x == 256) ----------------
__device__ __forceinline__ float block_reduce_sum(float v) {
    __shared__ float s[256];
    int t = threadIdx.x;
    s[t] = v;
    __syncthreads();
    #pragma unroll
    for (int st = 128; st > 0; st >>= 1) {
        if (t < st) s[t] += s[t + st];
        __syncthreads();
    }
    float r = s[0];
    __syncthreads();
    return r;
}

// ---------------- ternarize -> bf16 sign {-1,0,+1} + fp32 alpha ----------------
// perm9: write k' = tap*256 + ci for K=2304 (i = ci*9 + tap)
__global__ void ternarize_kernel(const float* __restrict__ w, short* __restrict__ wt,
                                 float* __restrict__ alpha, int K, int perm9) {
    int f = blockIdx.x;
    const float* wf = w + (size_t)f * K;
    short* wtf = wt + (size_t)f * K;

    float s = 0.f;
    for (int i = threadIdx.x; i < K; i += blockDim.x) s += fabsf(wf[i]);
    float total = block_reduce_sum(s);
    float delta = 0.7f * total / (float)K;

    float sm = 0.f, cm = 0.f;
    for (int i = threadIdx.x; i < K; i += blockDim.x) {
        float a = fabsf(wf[i]);
        if (a > delta) { sm += a; cm += 1.f; }
    }
    sm = block_reduce_sum(sm);
    cm = block_reduce_sum(cm);
    if (threadIdx.x == 0) alpha[f] = sm / (cm + 1e-8f);

    for (int i = threadIdx.x; i < K; i += blockDim.x) {
        float v = wf[i];
        float a = fabsf(v);
        short sv = (a > delta) ? ((v > 0.f) ? (short)0x3F80 : (short)0xBF80) : (short)0;
        int k = i;
        if (perm9) { int ci = i / 9; int tap = i - ci * 9; k = tap * 256 + ci; }
        wtf[k] = sv;
    }
}

// ---------------- fp32 -> bf16 cast ----------------
__global__ void f2bf_kernel(const float* __restrict__ in, short* __restrict__ out, int n) {
    int i = blockIdx.x * blockDim.x + threadIdx.x;
    if (i < n) out[i] = f2bs(in[i]);
}

// ---------------- fold scale into ternary signs: wf = sign * scale[k] ----------------
__global__ void foldw_kernel(const short* __restrict__ sign, const float* __restrict__ scale,
                             short* __restrict__ wf, int K, int total) {
    int i = blockIdx.x * blockDim.x + threadIdx.x;
    if (i >= total) return;
    int k = i % K;
    wf[i] = f2bs(bs2f(sign[i]) * scale[k]);
}

// ---------------- fold bias: bias[m] = alpha[m] * dot(sign[m,:], shift) ----------------
__global__ void foldb_kernel(const short* __restrict__ sign, const float* __restrict__ shift,
                             const float* __restrict__ alpha, float* __restrict__ bias, int K) {
    int m = blockIdx.x;
    float s = 0.f;
    for (int k = threadIdx.x; k < K; k += blockDim.x)
        s += bs2f(sign[(size_t)m * K + k]) * shift[k];
    s = block_reduce_sum(s);
    if (threadIdx.x == 0) bias[m] = alpha[m] * s;
}

// ---------------- column stats on T-layout [R][C] bf16 (scalar accums, no spill) ----------------
// Each thread owns a fixed 4-channel quad: with grid-stride = gridDim*256 divisible by C/4,
// quad index (i % (C/4)) == t % (C/4) is loop-invariant. 8 scalar accumulators in VGPRs.
// Requires gridDim.x*256 % (C/4) == 0 (C in {256,512,1024}, gridDim=256 -> ok).
template <int C>
__global__ __launch_bounds__(256) void colstats_kernel(
    const uint2* __restrict__ src, float* __restrict__ sum, float* __restrict__ sq,
    int totalVec2) {
    constexpr int C4 = C / 4;          // quads per row: 64 / 128 / 256
    constexpr int DUP = 256 / C4;      // threads sharing a quad within the block
    int t = threadIdx.x;
    float s0 = 0.f, s1 = 0.f, s2 = 0.f, s3 = 0.f;
    float q0 = 0.f, q1 = 0.f, q2 = 0.f, q3 = 0.f;
    for (int i = blockIdx.x * 256 + t; i < totalVec2; i += gridDim.x * 256) {
        uint2 v = src[i];
        float f0 = bs2f((short)(v.x & 0xffff));
        float f1 = bs2f((short)(v.x >> 16));
        float f2 = bs2f((short)(v.y & 0xffff));
        float f3 = bs2f((short)(v.y >> 16));
        s0 += f0; q0 += f0 * f0;
        s1 += f1; q1 += f1 * f1;
        s2 += f2; q2 += f2 * f2;
        s3 += f3; q3 += f3 * f3;
    }
    __shared__ float red[256][9];
    red[t][0] = s0; red[t][1] = s1; red[t][2] = s2; red[t][3] = s3;
    red[t][4] = q0; red[t][5] = q1; red[t][6] = q2; red[t][7] = q3;
    __syncthreads();
    if (t < C4) {
        #pragma unroll
        for (int d = 1; d < DUP; d++)
            #pragma unroll
            for (int k = 0; k < 8; k++) red[t][k] += red[t + d * C4][k];
        // quad for thread t is t (256 % C4 == 0)
        atomicAdd(&sum[4 * t + 0], red[t][0]);
        atomicAdd(&sum[4 * t + 1], red[t][1]);
        atomicAdd(&sum[4 * t + 2], red[t][2]);
        atomicAdd(&sum[4 * t + 3], red[t][3]);
        atomicAdd(&sq[4 * t + 0], red[t][4]);
        atomicAdd(&sq[4 * t + 1], red[t][5]);
        atomicAdd(&sq[4 * t + 2], red[t][6]);
        atomicAdd(&sq[4 * t + 3], red[t][7]);
    }
}

// ---------------- BN finalize ----------------
__global__ void bn_finalize_kernel(const float* __restrict__ sum, const float* __restrict__ sq,
                                   const float* __restrict__ g, const float* __restrict__ b,
                                   float* __restrict__ scale, float* __restrict__ shift,
                                   int C, float cnt) {
    int c = blockIdx.x * blockDim.x + threadIdx.x;
    if (c >= C) return;
    float mean = sum[c] / cnt;
    float var = fmaxf(sq[c] / cnt - mean * mean, 0.f);
    float r = rsqrtf(var + EPS);
    float sc = g[c] * r;
    scale[c] = sc;
    shift[c] = b[c] - mean * sc;
}

// ---------------- transpose NCHW fp32 -> xT[(n*SP+p)][C] bf16 (raw) ----------------
__global__ __launch_bounds__(256) void transpose_kernel(
    const float* __restrict__ in, short* __restrict__ Bt, int C, int SP) {
    __shared__ short tile[64][65];
    int n = blockIdx.z;
    int ci0 = blockIdx.y * 64;
    int p0 = blockIdx.x * 64;
    int tx = threadIdx.x & 63;
    int ty4 = threadIdx.x >> 6;

    int p = p0 + tx;
    bool pok = p < SP;
    const float* base = in + ((size_t)n * C + ci0) * SP;
    #pragma unroll
    for (int r = 0; r < 16; r++) {
        int ci = ty4 + r * 4;
        float v = 0.f;
        if (pok) v = base[(size_t)ci * SP + p];
        tile[tx][ci] = f2bs(v);
    }
    __syncthreads();
    #pragma unroll
    for (int r = 0; r < 16; r++) {
        int pl = ty4 + r * 4;
        int pw = p0 + pl;
        if (pw < SP)
            Bt[((size_t)n * SP + pw) * C + ci0 + tx] = tile[pl][tx];
    }
}

// ---------------- im2col (tap-major K) from h1t, with bn2 affine ----------------
__global__ void im2col_t_kernel(const short* __restrict__ h1t,
                                const float* __restrict__ scale, const float* __restrict__ shift,
                                short* __restrict__ B2t, int totalVec) {
    int i = blockIdx.x * blockDim.x + threadIdx.x;
    if (i >= totalVec) return;
    int cg = i & 31;
    int rest = i >> 5;
    int tap = rest % 9;
    int c = rest / 9;
    int kh = tap / 3, kw = tap - kh * 3;
    int n = c / 196, pp = c - n * 196;
    int oh = pp / 14, ow = pp - oh * 14;
    int ih = 2 * oh - 1 + kh, iw = 2 * ow - 1 + kw;
    short tmp[8];
    if ((unsigned)ih < 28u && (unsigned)iw < 28u) {
        int src = n * 784 + ih * 28 + iw;
        *(int4*)tmp = *(const int4*)(h1t + (size_t)src * 256 + cg * 8);
        #pragma unroll
        for (int k2 = 0; k2 < 8; k2++) {
            int ch = cg * 8 + k2;
            tmp[k2] = f2bs(bs2f(tmp[k2]) * scale[ch] + shift[ch]);
        }
    } else {
        #pragma unroll
        for (int k2 = 0; k2 < 8; k2++) tmp[k2] = 0;
    }
    *(int4*)(B2t + (size_t)c * 2304 + tap * 256 + cg * 8) = *(int4*)tmp;
}

// ---------------- flipped MFMA GEMM: D[pix][ch] ----------------
template <bool REMAP, int MODE, typename TOut>
__global__ __launch_bounds__(256) void gemm_t_kernel(
    const short* __restrict__ Act, const short* __restrict__ Wt,
    const float* __restrict__ alpha, const float* __restrict__ bias,
    TOut* __restrict__ outT, int M, int K) {
    __shared__ short As[128 * 32];
    __shared__ short Bs[128 * 32];
    int t = threadIdx.x;
    int pix0 = blockIdx.x * 128;
    int ch0 = blockIdx.y * 128;
    int w = t >> 6, l = t & 63;
    int wm = (w >> 1) * 64, wn = (w & 1) * 64;
    int r0 = t >> 2;
    int kg = (t & 3) * 8;

    int pr0 = pix0 + r0, pr1 = pix0 + r0 + 64;
    if (REMAP) {
        int n0 = pr0 / 196, pp0 = pr0 - n0 * 196, oh0 = pp0 / 14, ow0 = pp0 - oh0 * 14;
        pr0 = n0 * 784 + oh0 * 56 + ow0 * 2;
        int n1 = pr1 / 196, pp1 = pr1 - n1 * 196, oh1 = pp1 / 14, ow1 = pp1 - oh1 * 14;
        pr1 = n1 * 784 + oh1 * 56 + ow1 * 2;
    }
    const short* a0 = Act + (size_t)pr0 * K;
    const short* a1 = Act + (size_t)pr1 * K;
    const short* b0 = Wt + (size_t)(ch0 + r0) * K;
    const short* b1 = Wt + (size_t)(ch0 + r0 + 64) * K;

    float4v acc[4][4];
    #pragma unroll
    for (int i = 0; i < 4; i++)
        #pragma unroll
        for (int j = 0; j < 4; j++) acc[i][j] = (float4v)0.f;

    int lm = (l >> 4);
    int lc = l & 15;

    for (int k0 = 0; k0 < K; k0 += 32) {
        int4 av0 = *(const int4*)(a0 + k0 + kg);
        int4 av1 = *(const int4*)(a1 + k0 + kg);
        int4 bv0 = *(const int4*)(b0 + k0 + kg);
        int4 bv1 = *(const int4*)(b1 + k0 + kg);
        __syncthreads();
        *(int4*)&As[r0 * 32 + kg] = av0;
        *(int4*)&As[(r0 + 64) * 32 + kg] = av1;
        *(int4*)&Bs[r0 * 32 + kg] = bv0;
        *(int4*)&Bs[(r0 + 64) * 32 + kg] = bv1;
        __syncthreads();

        short8 af[4], bfr[4];
        #pragma unroll
        for (int i = 0; i < 4; i++)
            af[i] = *(const short8*)&As[(wm + i * 16 + lc) * 32 + lm * 8];
        #pragma unroll
        for (int j = 0; j < 4; j++)
            bfr[j] = *(const short8*)&Bs[(wn + j * 16 + lc) * 32 + lm * 8];
        #pragma unroll
        for (int i = 0; i < 4; i++)
            #pragma unroll
            for (int j = 0; j < 4; j++)
                acc[i][j] = __builtin_amdgcn_mfma_f32_16x16x32_bf16(af[i], bfr[j], acc[i][j], 0, 0, 0);
    }

    #pragma unroll
    for (int j = 0; j < 4; j++) {
        int col = ch0 + wn + j * 16 + lc;
        float al = (MODE >= 1) ? alpha[col] : 1.f;
        float bi = (MODE == 2) ? bias[col] : 0.f;
        #pragma unroll
        for (int i = 0; i < 4; i++) {
            #pragma unroll
            for (int r = 0; r < 4; r++) {
                int pix = pix0 + wm + i * 16 + lm * 4 + r;
                float v = acc[i][j][r] * al + bi;
                stF(&outT[(size_t)pix * M + col], v);
            }
        }
    }
}

// ---------------- final: out[n][c][p] = outT[pix][c] + scT[pix][c]*scale[c]+shift[c] ----------------
__global__ __launch_bounds__(256) void combine_kernel(
    const float* __restrict__ outT, const short* __restrict__ scT,
    const float* __restrict__ scale, const float* __restrict__ shift,
    float* __restrict__ out) {
    __shared__ float tile[64][65];
    int pix0 = blockIdx.x * 64;
    int ch0 = blockIdx.y * 64;
    int tx = threadIdx.x & 63;
    int ph = threadIdx.x >> 6;
    float sc_ = scale[ch0 + tx];
    float sh_ = shift[ch0 + tx];
    #pragma unroll
    for (int i2 = 0; i2 < 16; i2++) {
        int pr = ph + i2 * 4;
        size_t base = (size_t)(pix0 + pr) * 1024 + ch0 + tx;
        tile[pr][tx] = outT[base] + bs2f(scT[base]) * sc_ + sh_;
    }
    __syncthreads();
    int pix = pix0 + tx;
    int n = pix / 196, p = pix - n * 196;
    #pragma unroll
    for (int i2 = 0; i2 < 16; i2++) {
        int ch = ch0 + ph + i2 * 4;
        out[((size_t)n * 1024 + ch) * 196 + p] = tile[tx][ph + i2 * 4];
    }
}

extern "C" void kernel_launch(void* const* d_in, const int* in_sizes, int n_in,
                              void* d_out, int out_size, void* d_ws, size_t ws_size,
                              hipStream_t stream) {
    const float* x      = (const float*)d_in[0];
    const float* bn1_g  = (const float*)d_in[1];
    const float* bn1_b  = (const float*)d_in[2];
    const float* w1     = (const float*)d_in[3];
    const float* bn2_g  = (const float*)d_in[4];
    const float* bn2_b  = (const float*)d_in[5];
    const float* w2     = (const float*)d_in[6];
    const float* bn3_g  = (const float*)d_in[7];
    const float* bn3_b  = (const float*)d_in[8];
    const float* w3     = (const float*)d_in[9];
    const float* ds_w   = (const float*)d_in[10];  // NOT ternarized
    const float* dbn_g  = (const float*)d_in[11];
    const float* dbn_b  = (const float*)d_in[12];
    float* out = (float*)d_out;

    const int N = 64, C1 = 512, C2 = 256, C3 = 1024;
    const int SP1 = 784, SP2 = 196;
    const int NT1 = N * SP1;   // 50176
    const int NT2 = N * SP2;   // 12544

    char* wsb = (char*)d_ws;
    size_t off = 0;
    auto alloc = [&](size_t bytes) { char* p = wsb + off; off += (bytes + 255) & ~(size_t)255; return p; };

    char* pool = alloc((size_t)NT2 * 2304 * 2);
    short* xT   = (short*)pool;
    short* B2t  = (short*)pool;
    float* outT = (float*)pool;
    short* scT = (short*)alloc((size_t)NT2 * C3 * 2);
    short* h1t = (short*)alloc((size_t)NT1 * C2 * 2);
    short* h2t = (short*)alloc((size_t)NT2 * C2 * 2);
    short* w1t  = (short*)alloc((size_t)C2 * C1 * 2);
    short* w2t  = (short*)alloc((size_t)C2 * C2 * 9 * 2);
    short* w3t  = (short*)alloc((size_t)C3 * C2 * 2);
    short* dswb = (short*)alloc((size_t)C3 * C1 * 2);
    short* w1f  = (short*)alloc((size_t)C2 * C1 * 2);
    short* w3f  = (short*)alloc((size_t)C3 * C2 * 2);
    float* alpha1 = (float*)alloc(C2 * 4);
    float* alpha2 = (float*)alloc(C2 * 4);
    float* alpha3 = (float*)alloc(C3 * 4);
    float* bias1  = (float*)alloc(C2 * 4);
    float* bias3  = (float*)alloc(C3 * 4);
    float* scale1 = (float*)alloc(C1 * 4);
    float* shift1 = (float*)alloc(C1 * 4);
    float* scale2 = (float*)alloc(C2 * 4);
    float* shift2 = (float*)alloc(C2 * 4);
    float* scale3 = (float*)alloc(C2 * 4);
    float* shift3 = (float*)alloc(C2 * 4);
    float* scaled = (float*)alloc(C3 * 4);
    float* shiftd = (float*)alloc(C3 * 4);
    float* acc_base = (float*)alloc((size_t)(C1 + C2 + C2 + C3) * 2 * 4);
    float* sum1 = acc_base;  float* sq1 = sum1 + C1;
    float* sum2 = sq1 + C1;  float* sq2 = sum2 + C2;
    float* sum3 = sq2 + C2;  float* sq3 = sum3 + C2;
    float* sumd = sq3 + C2;  float* sqd = sumd + C3;
    (void)ws_size; (void)in_sizes; (void)n_in; (void)out_size;

    hipMemsetAsync(acc_base, 0, (size_t)(C1 + C2 + C2 + C3) * 2 * 4, stream);

    ternarize_kernel<<<C2, 256, 0, stream>>>(w1, w1t, alpha1, C1, 0);
    ternarize_kernel<<<C2, 256, 0, stream>>>(w2, w2t, alpha2, C2 * 9, 1);
    ternarize_kernel<<<C3, 256, 0, stream>>>(w3, w3t, alpha3, C2, 0);
    f2bf_kernel<<<(C3 * C1 + 255) / 256, 256, 0, stream>>>(ds_w, dswb, C3 * C1);

    // xT = transpose(x) raw bf16
    transpose_kernel<<<dim3(13, C1 / 64, N), 256, 0, stream>>>(x, xT, C1, SP1);

    // GEMM4 (ds conv): scT = xT[remap] . dswb^T   (M=1024, K=512)
    gemm_t_kernel<true, 0, short><<<dim3(NT2 / 128, C3 / 128), 256, 0, stream>>>(
        xT, dswb, nullptr, nullptr, scT, C3, C1);
    colstats_kernel<1024><<<256, 256, 0, stream>>>((const uint2*)scT, sumd, sqd, NT2 * (C3 / 4));
    bn_finalize_kernel<<<(C3 + 255) / 256, 256, 0, stream>>>(sumd, sqd, dbn_g, dbn_b,
                                                             scaled, shiftd, C3, (float)(NT2));

    // bn1 from xT; fold into w1
    colstats_kernel<512><<<256, 256, 0, stream>>>((const uint2*)xT, sum1, sq1, NT1 * (C1 / 4));
    bn_finalize_kernel<<<(C1 + 255) / 256, 256, 0, stream>>>(sum1, sq1, bn1_g, bn1_b,
                                                             scale1, shift1, C1, (float)(NT1));
    foldw_kernel<<<(C2 * C1 + 255) / 256, 256, 0, stream>>>(w1t, scale1, w1f, C1, C2 * C1);
    foldb_kernel<<<C2, 256, 0, stream>>>(w1t, shift1, alpha1, bias1, C1);

    // GEMM1: h1t = xT . w1f^T * alpha1 + bias1   (M=256, K=512)
    gemm_t_kernel<false, 2, short><<<dim3(NT1 / 128, C2 / 128), 256, 0, stream>>>(
        xT, w1f, alpha1, bias1, h1t, C2, C1);

    // bn2 from h1t; im2col with affine
    colstats_kernel<256><<<256, 256, 0, stream>>>((const uint2*)h1t, sum2, sq2, NT1 * (C2 / 4));
    bn_finalize_kernel<<<(C2 + 255) / 256, 256, 0, stream>>>(sum2, sq2, bn2_g, bn2_b,
                                                             scale2, shift2, C2, (float)(NT1));
    {
        int totalVec = NT2 * 288;
        im2col_t_kernel<<<(totalVec + 255) / 256, 256, 0, stream>>>(
            h1t, scale2, shift2, B2t, totalVec);
    }

    // GEMM2: h2t = B2t . w2t^T * alpha2   (M=256, K=2304)
    gemm_t_kernel<false, 1, short><<<dim3(NT2 / 128, C2 / 128), 256, 0, stream>>>(
        B2t, w2t, alpha2, nullptr, h2t, C2, C2 * 9);

    // bn3 from h2t; fold into w3
    colstats_kernel<256><<<256, 256, 0, stream>>>((const uint2*)h2t, sum3, sq3, NT2 * (C2 / 4));
    bn_finalize_kernel<<<(C2 + 255) / 256, 256, 0, stream>>>(sum3, sq3, bn3_g, bn3_b,
                                                             scale3, shift3, C2, (float)(NT2));
    foldw_kernel<<<(C3 * C2 + 255) / 256, 256, 0, stream>>>(w3t, scale3, w3f, C2, C3 * C2);
    foldb_kernel<<<C3, 256, 0, stream>>>(w3t, shift3, alpha3, bias3, C2);

    // GEMM3: outT = h2t . w3f^T * alpha3 + bias3   (M=1024, K=256, fp32 out)
    gemm_t_kernel<false, 2, float><<<dim3(NT2 / 128, C3 / 128), 256, 0, stream>>>(
        h2t, w3f, alpha3, bias3, outT, C3, C2);

    // final: out = outT + dsbn(scT), transposed to NCHW
    combine_kernel<<<dim3(NT2 / 64, C3 / 64), 256, 0, stream>>>(
        outT, scT, scaled, shiftd, out);
}